// Round 19
// baseline (2209.917 us; speedup 1.0000x reference)
//
#include <hip/hip_runtime.h>

#define BB 64
#define SS 2048
#define II 128
#define HH 256
#define OO 128

typedef _Float16 h2_t __attribute__((ext_vector_type(2)));

// v11 lesson: dot2 WAS being emitted, and ~930 VALU-cyc/SIMD/step implies
// v_dot2_f32_f16 issues at ~1/4 rate (8 cyc/wave64). Replace with
// v_fma_mix_f32 (full-rate FMA pipe, f16 sources, f32 accumulate):
// 2 instr per f16 pair @ 2 cyc beats 1 dot2 @ 8 cyc.
__device__ __forceinline__ float fdot2(unsigned h, unsigned w, float acc) {
    float r;
    asm("v_fma_mix_f32 %0, %1, %2, %3 op_sel_hi:[1,1,0]"
        : "=v"(r) : "v"(h), "v"(w), "v"(acc));
    asm("v_fma_mix_f32 %0, %1, %2, %3 op_sel:[1,1,0] op_sel_hi:[1,1,0]"
        : "=v"(r) : "v"(h), "v"(w), "v"(r));
    return r;
}

// ---------------------------------------------------------------------------
// Prep: transpose W_ih -> [I][H], W_fc -> [H][O], combine biases, and write
// the SWIZZLED f16 weight buffer wsw (v9 layout, unchanged):
//   uint4 slot s = (w*16 + pair*8 + i)*64 + l  holds the chunk thread
//   (wave w, lane l) consumes as wA[i] (pair=0) / wB[i] (pair=1):
//   row j = w*32 + (l&15)*2 + pair, dwords (l>>4)*32 + i*4 .. +3.
// ---------------------------------------------------------------------------
__global__ void prep_kernel(const float* __restrict__ W_ih, const float* __restrict__ b_ih,
                            const float* __restrict__ b_hh, const float* __restrict__ W_fc,
                            float* __restrict__ wihT, float* __restrict__ wfcT,
                            float* __restrict__ biasc, unsigned* __restrict__ wsw,
                            const float* __restrict__ W_hh) {
    int idx = blockIdx.x * 256 + threadIdx.x;      // grid 128*256 = 32768
    if (idx < HH * II) {            // W_ih [H][I] -> wihT [I][H]
        int j = idx / II, k = idx % II;
        wihT[k * HH + j] = W_ih[idx];
    }
    if (idx < OO * HH) {            // W_fc [O][H] -> wfcT [H][O]
        int j = idx / HH, k = idx % HH;
        wfcT[k * OO + j] = W_fc[idx];
    }
    if (idx < HH * (HH / 2)) {      // swizzled scan weights (32768 dwords)
        int d   = idx & 3;
        int s   = idx >> 2;
        int l   = s & 63;
        int rem = s >> 6;
        int i    = rem & 7;
        int pair = (rem >> 3) & 1;
        int w    = rem >> 4;
        int j    = w * 32 + (l & 15) * 2 + pair;
        int word = (l >> 4) * 32 + i * 4 + d;      // dword index within row j
        union { h2_t h; unsigned u; } pk;
        pk.h.x = (_Float16)W_hh[j * HH + 2 * word];
        pk.h.y = (_Float16)W_hh[j * HH + 2 * word + 1];
        wsw[idx] = pk.u;
    }
    if (idx < HH) biasc[idx] = b_ih[idx] + b_hh[idx];
}

// ---------------------------------------------------------------------------
// Generic row-major GEMM: C[r][j] = sum_k A[r][k] * Wt[k][j] + bias[j]
// 256 threads, 8x8 micro-tile per thread. (unchanged — scan dominates)
// ---------------------------------------------------------------------------
template<int KD, int JD, int RT>
__global__ __launch_bounds__(256, 2)
void gemm_rk(const float* __restrict__ A, const float* __restrict__ Wt,
             const float* __restrict__ bias, float* __restrict__ C) {
    constexpr int KT = 64;
    constexpr int TJ = JD / 8;
    constexpr int TR = RT / 8;
    static_assert(TJ * TR == 256, "bad tiling");

    __shared__ __align__(16) float a_lds[RT][KT];
    __shared__ __align__(16) float w_lds[KT][JD];

    const int tid = threadIdx.x;
    const int tj = tid % TJ;
    const int tr = tid / TJ;
    const long r0 = (long)blockIdx.x * RT;

    float acc[8][8];
#pragma unroll
    for (int r = 0; r < 8; ++r)
#pragma unroll
        for (int j = 0; j < 8; ++j) acc[r][j] = 0.0f;

    for (int kt = 0; kt < KD; kt += KT) {
        {
            constexpr int NF4 = RT * KT / 4;
#pragma unroll
            for (int f = 0; f < NF4 / 256; ++f) {
                int fl = f * 256 + tid;
                int rr = fl / (KT / 4), kk4 = fl % (KT / 4);
                *(float4*)&a_lds[rr][kk4 * 4] =
                    *(const float4*)&A[(r0 + rr) * KD + kt + kk4 * 4];
            }
        }
        {
            constexpr int NF4 = KT * JD / 4;
#pragma unroll
            for (int f = 0; f < NF4 / 256; ++f) {
                int fl = f * 256 + tid;
                int kk = fl / (JD / 4), jj4 = fl % (JD / 4);
                *(float4*)&w_lds[kk][jj4 * 4] =
                    *(const float4*)&Wt[(long)(kt + kk) * JD + jj4 * 4];
            }
        }
        __syncthreads();

#pragma unroll 4
        for (int k4 = 0; k4 < KT; k4 += 4) {
            float4 xv[8];
#pragma unroll
            for (int r = 0; r < 8; ++r)
                xv[r] = *(const float4*)&a_lds[tr * 8 + r][k4];
#pragma unroll
            for (int i = 0; i < 4; ++i) {
                float4 wa = *(const float4*)&w_lds[k4 + i][tj * 8];
                float4 wb = *(const float4*)&w_lds[k4 + i][tj * 8 + 4];
#pragma unroll
                for (int r = 0; r < 8; ++r) {
                    float xs = (i == 0) ? xv[r].x : (i == 1) ? xv[r].y
                             : (i == 2) ? xv[r].z : xv[r].w;
                    acc[r][0] = fmaf(xs, wa.x, acc[r][0]);
                    acc[r][1] = fmaf(xs, wa.y, acc[r][1]);
                    acc[r][2] = fmaf(xs, wa.z, acc[r][2]);
                    acc[r][3] = fmaf(xs, wa.w, acc[r][3]);
                    acc[r][4] = fmaf(xs, wb.x, acc[r][4]);
                    acc[r][5] = fmaf(xs, wb.y, acc[r][5]);
                    acc[r][6] = fmaf(xs, wb.z, acc[r][6]);
                    acc[r][7] = fmaf(xs, wb.w, acc[r][7]);
                }
            }
        }
        __syncthreads();
    }

    float4 b0 = *(const float4*)&bias[tj * 8];
    float4 b1 = *(const float4*)&bias[tj * 8 + 4];
#pragma unroll
    for (int r = 0; r < 8; ++r) {
        long row = r0 + tr * 8 + r;
        float4 o0, o1;
        o0.x = acc[r][0] + b0.x; o0.y = acc[r][1] + b0.y;
        o0.z = acc[r][2] + b0.z; o0.w = acc[r][3] + b0.w;
        o1.x = acc[r][4] + b1.x; o1.y = acc[r][5] + b1.y;
        o1.z = acc[r][6] + b1.z; o1.w = acc[r][7] + b1.w;
        *(float4*)&C[row * JD + tj * 8]     = o0;
        *(float4*)&C[row * JD + tj * 8 + 4] = o1;
    }
}

// ---------------------------------------------------------------------------
// Sequential scan v12 = v9 (best measured: 1256us) with the MAC instruction
// swapped: v_fma_mix_f32 (full-rate) instead of v_dot2_f32_f16 (~1/4-rate).
// Everything else identical: 64 blocks x 512 threads, weights stream from
// L2 (swizzled, coalesced), double-buffered f16 h in LDS, butterfly
// shfl_xor(16,32) reduce, one barrier per step.
// ---------------------------------------------------------------------------
__global__ __attribute__((amdgpu_waves_per_eu(2, 2))) __launch_bounds__(512)
void rnn_scan(const unsigned* __restrict__ wsw, float* __restrict__ hid) {
    const int b   = blockIdx.x;
    const int tid = threadIdx.x;
    const int w   = tid >> 6;
    const int l   = tid & 63;
    const int sl  = l & 15;
    const int q   = l >> 4;

    const int j0 = w * 32 + sl * 2;      // two outputs j0, j0+1

    __shared__ __align__(16) unsigned h16[2][4 * 36];

    // per-thread weight stream base: lane-consecutive 16B chunks
    const uint4* __restrict__ wp = (const uint4*)wsw + ((size_t)w << 10) + l;

    for (int i = tid; i < 2 * 4 * 36; i += 512) ((unsigned*)h16)[i] = 0u;

    float* __restrict__ base = hid + (size_t)b * SS * HH;
    float2 xp0 = *(const float2*)&base[j0];
    float2 xp1 = *(const float2*)&base[HH + j0];
    __syncthreads();

#pragma unroll 1
    for (int t = 0; t < SS; ++t) {
        // weight stream for this step (L2-resident, coalesced):
        // wA[i] at slot (w*16+i)*64+l, wB[i] at slot (w*16+8+i)*64+l
        uint4 wA[8], wB[8];
#pragma unroll
        for (int i = 0; i < 8; ++i) {
            wA[i] = wp[i * 64];
            wB[i] = wp[(8 + i) * 64];
        }

        // prefetch xproj for t+2 (read precedes the overwrite at t)
        float2 xp2 = make_float2(0.f, 0.f);
        if (t + 2 < SS) xp2 = *(const float2*)&base[(size_t)(t + 2) * HH + j0];

        const uint4* hb = (const uint4*)&h16[t & 1][q * 36];
        float aA0 = 0.f, aA1 = 0.f, aB0 = 0.f, aB1 = 0.f;
#pragma unroll
        for (int i = 0; i < 8; ++i) {
            uint4 hv = hb[i];
            aA0 = fdot2(hv.x, wA[i].x, aA0);
            aA1 = fdot2(hv.y, wA[i].y, aA1);
            aA0 = fdot2(hv.z, wA[i].z, aA0);
            aA1 = fdot2(hv.w, wA[i].w, aA1);
            aB0 = fdot2(hv.x, wB[i].x, aB0);
            aB1 = fdot2(hv.y, wB[i].y, aB1);
            aB0 = fdot2(hv.z, wB[i].z, aB0);
            aB1 = fdot2(hv.w, wB[i].w, aB1);
        }
        float sA = aA0 + aA1;
        float sB = aB0 + aB1;
        // butterfly over the 4 k-quarters (lanes sl, sl+16, sl+32, sl+48)
        sA += __shfl_xor(sA, 16, 64);
        sA += __shfl_xor(sA, 32, 64);
        sB += __shfl_xor(sB, 16, 64);
        sB += __shfl_xor(sB, 32, 64);

        float s0 = xp0.x + sA;
        float s1 = xp0.y + sB;
        // tanh(s) = 1 - 2/(e^{2s}+1); overflow-safe without clamps
        float e0  = __expf(2.0f * s0);
        float e1  = __expf(2.0f * s1);
        float hn0 = 1.0f - __fdividef(2.0f, e0 + 1.0f);
        float hn1 = 1.0f - __fdividef(2.0f, e1 + 1.0f);

        if (q == 0) {
            union { h2_t h; unsigned u; } pk;
            pk.h.x = (_Float16)hn0;
            pk.h.y = (_Float16)hn1;
            const int W = j0 >> 1;
            h16[(t & 1) ^ 1][(W >> 5) * 36 + (W & 31)] = pk.u;
            *(float2*)&base[(size_t)t * HH + j0] = make_float2(hn0, hn1);
        }
        __syncthreads();
        xp0 = xp1;
        xp1 = xp2;
    }
}

// ---------------------------------------------------------------------------
extern "C" void kernel_launch(void* const* d_in, const int* in_sizes, int n_in,
                              void* d_out, int out_size, void* d_ws, size_t ws_size,
                              hipStream_t stream) {
    const float* x    = (const float*)d_in[0];
    const float* W_ih = (const float*)d_in[1];
    const float* W_hh = (const float*)d_in[2];
    const float* b_ih = (const float*)d_in[3];
    const float* b_hh = (const float*)d_in[4];
    const float* W_fc = (const float*)d_in[5];
    const float* b_fc = (const float*)d_in[6];

    float* out_fc  = (float*)d_out;                          // [B][S][O]
    float* hidden  = (float*)d_out + (size_t)BB * SS * OO;   // [B][S][H]

    float*    wihT  = (float*)d_ws;                  // [I][H]  32768 f
    float*    wfcT  = wihT + II * HH;                // [H][O]  32768 f
    float*    biasc = wfcT + HH * OO;                // [H]       256 f
    unsigned* wsw   = (unsigned*)(biasc + HH);       // swizzled [32768] u32

    const long NR = (long)BB * SS;                   // 131072 rows

    prep_kernel<<<128, 256, 0, stream>>>(W_ih, b_ih, b_hh, W_fc,
                                         wihT, wfcT, biasc, wsw, W_hh);
    gemm_rk<II, HH, 64><<<NR / 64, 256, 0, stream>>>(x, wihT, biasc, hidden);
    rnn_scan<<<BB, 512, 0, stream>>>(wsw, hidden);
    gemm_rk<HH, OO, 128><<<NR / 128, 256, 0, stream>>>(hidden, wfcT, b_fc, out_fc);
}

// Round 20
// 1771.572 us; speedup vs baseline: 1.2474x; 1.2474x over previous
//
#include <hip/hip_runtime.h>

#define BB 64
#define SS 2048
#define II 128
#define HH 256
#define OO 128

typedef _Float16 h2_t __attribute__((ext_vector_type(2)));

__device__ __forceinline__ h2_t u2h(unsigned u) {
    union { unsigned u; h2_t h; } c; c.u = u; return c.h;
}

// v11/v12 lesson: v_dot2_f32_f16 AND v_fma_mix_f32 both run on a slow
// mixed-precision path (~5-8 cyc effective). v_pk_fma_f16 is the standard
// full-rate packed pipe (2 MACs / 2 cyc). Let clang emit it from native
// h2_t arithmetic (no inline asm -> scheduler stays free).
__device__ __forceinline__ h2_t pkfma(unsigned h, unsigned w, h2_t acc) {
    return u2h(h) * u2h(w) + acc;
}

// ---------------------------------------------------------------------------
// Prep: transpose W_ih -> [I][H], W_fc -> [H][O], combine biases, and write
// the SWIZZLED f16 weight buffer wsw (v9 layout, unchanged):
//   uint4 slot s = (w*16 + pair*8 + i)*64 + l  holds the chunk thread
//   (wave w, lane l) consumes as wA[i] (pair=0) / wB[i] (pair=1):
//   row j = w*32 + (l&15)*2 + pair, dwords (l>>4)*32 + i*4 .. +3.
// ---------------------------------------------------------------------------
__global__ void prep_kernel(const float* __restrict__ W_ih, const float* __restrict__ b_ih,
                            const float* __restrict__ b_hh, const float* __restrict__ W_fc,
                            float* __restrict__ wihT, float* __restrict__ wfcT,
                            float* __restrict__ biasc, unsigned* __restrict__ wsw,
                            const float* __restrict__ W_hh) {
    int idx = blockIdx.x * 256 + threadIdx.x;      // grid 128*256 = 32768
    if (idx < HH * II) {            // W_ih [H][I] -> wihT [I][H]
        int j = idx / II, k = idx % II;
        wihT[k * HH + j] = W_ih[idx];
    }
    if (idx < OO * HH) {            // W_fc [O][H] -> wfcT [H][O]
        int j = idx / HH, k = idx % HH;
        wfcT[k * OO + j] = W_fc[idx];
    }
    if (idx < HH * (HH / 2)) {      // swizzled scan weights (32768 dwords)
        int d   = idx & 3;
        int s   = idx >> 2;
        int l   = s & 63;
        int rem = s >> 6;
        int i    = rem & 7;
        int pair = (rem >> 3) & 1;
        int w    = rem >> 4;
        int j    = w * 32 + (l & 15) * 2 + pair;
        int word = (l >> 4) * 32 + i * 4 + d;      // dword index within row j
        union { h2_t h; unsigned u; } pk;
        pk.h.x = (_Float16)W_hh[j * HH + 2 * word];
        pk.h.y = (_Float16)W_hh[j * HH + 2 * word + 1];
        wsw[idx] = pk.u;
    }
    if (idx < HH) biasc[idx] = b_ih[idx] + b_hh[idx];
}

// ---------------------------------------------------------------------------
// Generic row-major GEMM: C[r][j] = sum_k A[r][k] * Wt[k][j] + bias[j]
// 256 threads, 8x8 micro-tile per thread. (unchanged — scan dominates)
// ---------------------------------------------------------------------------
template<int KD, int JD, int RT>
__global__ __launch_bounds__(256, 2)
void gemm_rk(const float* __restrict__ A, const float* __restrict__ Wt,
             const float* __restrict__ bias, float* __restrict__ C) {
    constexpr int KT = 64;
    constexpr int TJ = JD / 8;
    constexpr int TR = RT / 8;
    static_assert(TJ * TR == 256, "bad tiling");

    __shared__ __align__(16) float a_lds[RT][KT];
    __shared__ __align__(16) float w_lds[KT][JD];

    const int tid = threadIdx.x;
    const int tj = tid % TJ;
    const int tr = tid / TJ;
    const long r0 = (long)blockIdx.x * RT;

    float acc[8][8];
#pragma unroll
    for (int r = 0; r < 8; ++r)
#pragma unroll
        for (int j = 0; j < 8; ++j) acc[r][j] = 0.0f;

    for (int kt = 0; kt < KD; kt += KT) {
        {
            constexpr int NF4 = RT * KT / 4;
#pragma unroll
            for (int f = 0; f < NF4 / 256; ++f) {
                int fl = f * 256 + tid;
                int rr = fl / (KT / 4), kk4 = fl % (KT / 4);
                *(float4*)&a_lds[rr][kk4 * 4] =
                    *(const float4*)&A[(r0 + rr) * KD + kt + kk4 * 4];
            }
        }
        {
            constexpr int NF4 = KT * JD / 4;
#pragma unroll
            for (int f = 0; f < NF4 / 256; ++f) {
                int fl = f * 256 + tid;
                int kk = fl / (JD / 4), jj4 = fl % (JD / 4);
                *(float4*)&w_lds[kk][jj4 * 4] =
                    *(const float4*)&Wt[(long)(kt + kk) * JD + jj4 * 4];
            }
        }
        __syncthreads();

#pragma unroll 4
        for (int k4 = 0; k4 < KT; k4 += 4) {
            float4 xv[8];
#pragma unroll
            for (int r = 0; r < 8; ++r)
                xv[r] = *(const float4*)&a_lds[tr * 8 + r][k4];
#pragma unroll
            for (int i = 0; i < 4; ++i) {
                float4 wa = *(const float4*)&w_lds[k4 + i][tj * 8];
                float4 wb = *(const float4*)&w_lds[k4 + i][tj * 8 + 4];
#pragma unroll
                for (int r = 0; r < 8; ++r) {
                    float xs = (i == 0) ? xv[r].x : (i == 1) ? xv[r].y
                             : (i == 2) ? xv[r].z : xv[r].w;
                    acc[r][0] = fmaf(xs, wa.x, acc[r][0]);
                    acc[r][1] = fmaf(xs, wa.y, acc[r][1]);
                    acc[r][2] = fmaf(xs, wa.z, acc[r][2]);
                    acc[r][3] = fmaf(xs, wa.w, acc[r][3]);
                    acc[r][4] = fmaf(xs, wb.x, acc[r][4]);
                    acc[r][5] = fmaf(xs, wb.y, acc[r][5]);
                    acc[r][6] = fmaf(xs, wb.z, acc[r][6]);
                    acc[r][7] = fmaf(xs, wb.w, acc[r][7]);
                }
            }
        }
        __syncthreads();
    }

    float4 b0 = *(const float4*)&bias[tj * 8];
    float4 b1 = *(const float4*)&bias[tj * 8 + 4];
#pragma unroll
    for (int r = 0; r < 8; ++r) {
        long row = r0 + tr * 8 + r;
        float4 o0, o1;
        o0.x = acc[r][0] + b0.x; o0.y = acc[r][1] + b0.y;
        o0.z = acc[r][2] + b0.z; o0.w = acc[r][3] + b0.w;
        o1.x = acc[r][4] + b1.x; o1.y = acc[r][5] + b1.y;
        o1.z = acc[r][6] + b1.z; o1.w = acc[r][7] + b1.w;
        *(float4*)&C[row * JD + tj * 8]     = o0;
        *(float4*)&C[row * JD + tj * 8 + 4] = o1;
    }
}

// ---------------------------------------------------------------------------
// Sequential scan v13 = v9 (best measured: 1256us) with the MAC moved to
// v_pk_fma_f16 (full-rate packed pipe). Accumulation: 8 f16x2 chains (4 per
// output, 8 products per f16 slot -> bounded roundoff), merged to f32 at
// the end. Everything else identical to v9: 64 blocks x 512 threads,
// weights stream from L2 (swizzled, coalesced), double-buffered f16 h in
// LDS, butterfly shfl_xor(16,32) reduce, one barrier per step.
// ---------------------------------------------------------------------------
__global__ __attribute__((amdgpu_waves_per_eu(2, 2))) __launch_bounds__(512)
void rnn_scan(const unsigned* __restrict__ wsw, float* __restrict__ hid) {
    const int b   = blockIdx.x;
    const int tid = threadIdx.x;
    const int w   = tid >> 6;
    const int l   = tid & 63;
    const int sl  = l & 15;
    const int q   = l >> 4;

    const int j0 = w * 32 + sl * 2;      // two outputs j0, j0+1

    __shared__ __align__(16) unsigned h16[2][4 * 36];

    // per-thread weight stream base: lane-consecutive 16B chunks
    const uint4* __restrict__ wp = (const uint4*)wsw + ((size_t)w << 10) + l;

    for (int i = tid; i < 2 * 4 * 36; i += 512) ((unsigned*)h16)[i] = 0u;

    float* __restrict__ base = hid + (size_t)b * SS * HH;
    float2 xp0 = *(const float2*)&base[j0];
    float2 xp1 = *(const float2*)&base[HH + j0];
    __syncthreads();

#pragma unroll 1
    for (int t = 0; t < SS; ++t) {
        // weight stream for this step (L2-resident, coalesced):
        // wA[i] at slot (w*16+i)*64+l, wB[i] at slot (w*16+8+i)*64+l
        uint4 wA[8], wB[8];
#pragma unroll
        for (int i = 0; i < 8; ++i) {
            wA[i] = wp[i * 64];
            wB[i] = wp[(8 + i) * 64];
        }

        // prefetch xproj for t+2 (read precedes the overwrite at t)
        float2 xp2 = make_float2(0.f, 0.f);
        if (t + 2 < SS) xp2 = *(const float2*)&base[(size_t)(t + 2) * HH + j0];

        const uint4* hb = (const uint4*)&h16[t & 1][q * 36];
        // 8 packed-f16 accumulator chains (4 per output), 8 products/slot
        h2_t aA[4] = {{0,0},{0,0},{0,0},{0,0}};
        h2_t aB[4] = {{0,0},{0,0},{0,0},{0,0}};
#pragma unroll
        for (int i = 0; i < 8; ++i) {
            uint4 hv = hb[i];
            aA[0] = pkfma(hv.x, wA[i].x, aA[0]);
            aA[1] = pkfma(hv.y, wA[i].y, aA[1]);
            aA[2] = pkfma(hv.z, wA[i].z, aA[2]);
            aA[3] = pkfma(hv.w, wA[i].w, aA[3]);
            aB[0] = pkfma(hv.x, wB[i].x, aB[0]);
            aB[1] = pkfma(hv.y, wB[i].y, aB[1]);
            aB[2] = pkfma(hv.z, wB[i].z, aB[2]);
            aB[3] = pkfma(hv.w, wB[i].w, aB[3]);
        }
        float sA = ((float)aA[0].x + (float)aA[0].y) + ((float)aA[1].x + (float)aA[1].y)
                 + ((float)aA[2].x + (float)aA[2].y) + ((float)aA[3].x + (float)aA[3].y);
        float sB = ((float)aB[0].x + (float)aB[0].y) + ((float)aB[1].x + (float)aB[1].y)
                 + ((float)aB[2].x + (float)aB[2].y) + ((float)aB[3].x + (float)aB[3].y);

        // butterfly over the 4 k-quarters (lanes sl, sl+16, sl+32, sl+48)
        sA += __shfl_xor(sA, 16, 64);
        sA += __shfl_xor(sA, 32, 64);
        sB += __shfl_xor(sB, 16, 64);
        sB += __shfl_xor(sB, 32, 64);

        float s0 = xp0.x + sA;
        float s1 = xp0.y + sB;
        // tanh(s) = 1 - 2/(e^{2s}+1); overflow-safe without clamps
        float e0  = __expf(2.0f * s0);
        float e1  = __expf(2.0f * s1);
        float hn0 = 1.0f - __fdividef(2.0f, e0 + 1.0f);
        float hn1 = 1.0f - __fdividef(2.0f, e1 + 1.0f);

        if (q == 0) {
            union { h2_t h; unsigned u; } pk;
            pk.h.x = (_Float16)hn0;
            pk.h.y = (_Float16)hn1;
            const int W = j0 >> 1;
            h16[(t & 1) ^ 1][(W >> 5) * 36 + (W & 31)] = pk.u;
            *(float2*)&base[(size_t)t * HH + j0] = make_float2(hn0, hn1);
        }
        __syncthreads();
        xp0 = xp1;
        xp1 = xp2;
    }
}

// ---------------------------------------------------------------------------
extern "C" void kernel_launch(void* const* d_in, const int* in_sizes, int n_in,
                              void* d_out, int out_size, void* d_ws, size_t ws_size,
                              hipStream_t stream) {
    const float* x    = (const float*)d_in[0];
    const float* W_ih = (const float*)d_in[1];
    const float* W_hh = (const float*)d_in[2];
    const float* b_ih = (const float*)d_in[3];
    const float* b_hh = (const float*)d_in[4];
    const float* W_fc = (const float*)d_in[5];
    const float* b_fc = (const float*)d_in[6];

    float* out_fc  = (float*)d_out;                          // [B][S][O]
    float* hidden  = (float*)d_out + (size_t)BB * SS * OO;   // [B][S][H]

    float*    wihT  = (float*)d_ws;                  // [I][H]  32768 f
    float*    wfcT  = wihT + II * HH;                // [H][O]  32768 f
    float*    biasc = wfcT + HH * OO;                // [H]       256 f
    unsigned* wsw   = (unsigned*)(biasc + HH);       // swizzled [32768] u32

    const long NR = (long)BB * SS;                   // 131072 rows

    prep_kernel<<<128, 256, 0, stream>>>(W_ih, b_ih, b_hh, W_fc,
                                         wihT, wfcT, biasc, wsw, W_hh);
    gemm_rk<II, HH, 64><<<NR / 64, 256, 0, stream>>>(x, wihT, biasc, hidden);
    rnn_scan<<<BB, 512, 0, stream>>>(wsw, hidden);
    gemm_rk<HH, OO, 128><<<NR / 128, 256, 0, stream>>>(hidden, wfcT, b_fc, out_fc);
}

// Round 21
// 1397.458 us; speedup vs baseline: 1.5814x; 1.2677x over previous
//
#include <hip/hip_runtime.h>

#define BB 64
#define SS 2048
#define II 128
#define HH 256
#define OO 128

typedef _Float16 h2_t  __attribute__((ext_vector_type(2)));
typedef _Float16 half8 __attribute__((ext_vector_type(8)));
typedef float    f32x4 __attribute__((ext_vector_type(4)));

__device__ __forceinline__ h2_t u2h(unsigned u) {
    union { unsigned u; h2_t h; } c; c.u = u; return c.h;
}

#if __has_builtin(__builtin_amdgcn_fdot2)
__device__ __forceinline__ float fdot2(unsigned h, unsigned w, float acc) {
    return __builtin_amdgcn_fdot2(u2h(h), u2h(w), acc, false);
}
#else
__device__ __forceinline__ float fdot2(unsigned h, unsigned w, float acc) {
    h2_t hh = u2h(h), ww = u2h(w);
    acc = fmaf((float)hh.x, (float)ww.x, acc);
    acc = fmaf((float)hh.y, (float)ww.y, acc);
    return acc;
}
#endif

// ---------------------------------------------------------------------------
// Prep: transpose W_ih -> [I][H], combine biases, write the swizzled scan
// weights wsw (v9 layout), and pack W_fc into MFMA A-fragment order wfcp:
//   uint4 slot s = (jt*8 + kt)*64 + l holds A[row = jt*16 + (l&15)]
//   [k = kt*32 + (l>>4)*8 .. +7] as 8 f16 (pairs packed low/high).
// ---------------------------------------------------------------------------
__global__ void prep_kernel(const float* __restrict__ W_ih, const float* __restrict__ b_ih,
                            const float* __restrict__ b_hh, const float* __restrict__ W_fc,
                            float* __restrict__ wihT, float* __restrict__ biasc,
                            unsigned* __restrict__ wsw, unsigned* __restrict__ wfcp,
                            const float* __restrict__ W_hh) {
    int idx = blockIdx.x * 256 + threadIdx.x;      // grid 128*256 = 32768
    if (idx < HH * II) {            // W_ih [H][I] -> wihT [I][H]
        int j = idx / II, k = idx % II;
        wihT[k * HH + j] = W_ih[idx];
    }
    if (idx < HH * (HH / 2)) {      // swizzled scan weights (32768 dwords)
        int d   = idx & 3;
        int s   = idx >> 2;
        int l   = s & 63;
        int rem = s >> 6;
        int i    = rem & 7;
        int pair = (rem >> 3) & 1;
        int w    = rem >> 4;
        int j    = w * 32 + (l & 15) * 2 + pair;
        int word = (l >> 4) * 32 + i * 4 + d;      // dword index within row j
        union { h2_t h; unsigned u; } pk;
        pk.h.x = (_Float16)W_hh[j * HH + 2 * word];
        pk.h.y = (_Float16)W_hh[j * HH + 2 * word + 1];
        wsw[idx] = pk.u;
    }
    if (idx < 8 * 8 * 64 * 4) {     // wfcp: W_fc MFMA fragments (16384 dwords)
        int d    = idx & 3;
        int slot = idx >> 2;
        int l    = slot & 63;
        int kt   = (slot >> 6) & 7;
        int jt   = slot >> 9;
        int j    = jt * 16 + (l & 15);
        int k0   = kt * 32 + (l >> 4) * 8 + d * 2;
        union { h2_t h; unsigned u; } pk;
        pk.h.x = (_Float16)W_fc[j * HH + k0];
        pk.h.y = (_Float16)W_fc[j * HH + k0 + 1];
        wfcp[idx] = pk.u;
    }
    if (idx < HH) biasc[idx] = b_ih[idx] + b_hh[idx];
}

// ---------------------------------------------------------------------------
// GEMM1 (fp32, unchanged): C[r][j] = sum_k A[r][k] * Wt[k][j] + bias[j]
// ---------------------------------------------------------------------------
template<int KD, int JD, int RT>
__global__ __launch_bounds__(256, 2)
void gemm_rk(const float* __restrict__ A, const float* __restrict__ Wt,
             const float* __restrict__ bias, float* __restrict__ C) {
    constexpr int KT = 64;
    constexpr int TJ = JD / 8;
    constexpr int TR = RT / 8;
    static_assert(TJ * TR == 256, "bad tiling");

    __shared__ __align__(16) float a_lds[RT][KT];
    __shared__ __align__(16) float w_lds[KT][JD];

    const int tid = threadIdx.x;
    const int tj = tid % TJ;
    const int tr = tid / TJ;
    const long r0 = (long)blockIdx.x * RT;

    float acc[8][8];
#pragma unroll
    for (int r = 0; r < 8; ++r)
#pragma unroll
        for (int j = 0; j < 8; ++j) acc[r][j] = 0.0f;

    for (int kt = 0; kt < KD; kt += KT) {
        {
            constexpr int NF4 = RT * KT / 4;
#pragma unroll
            for (int f = 0; f < NF4 / 256; ++f) {
                int fl = f * 256 + tid;
                int rr = fl / (KT / 4), kk4 = fl % (KT / 4);
                *(float4*)&a_lds[rr][kk4 * 4] =
                    *(const float4*)&A[(r0 + rr) * KD + kt + kk4 * 4];
            }
        }
        {
            constexpr int NF4 = KT * JD / 4;
#pragma unroll
            for (int f = 0; f < NF4 / 256; ++f) {
                int fl = f * 256 + tid;
                int kk = fl / (JD / 4), jj4 = fl % (JD / 4);
                *(float4*)&w_lds[kk][jj4 * 4] =
                    *(const float4*)&Wt[(long)(kt + kk) * JD + jj4 * 4];
            }
        }
        __syncthreads();

#pragma unroll 4
        for (int k4 = 0; k4 < KT; k4 += 4) {
            float4 xv[8];
#pragma unroll
            for (int r = 0; r < 8; ++r)
                xv[r] = *(const float4*)&a_lds[tr * 8 + r][k4];
#pragma unroll
            for (int i = 0; i < 4; ++i) {
                float4 wa = *(const float4*)&w_lds[k4 + i][tj * 8];
                float4 wb = *(const float4*)&w_lds[k4 + i][tj * 8 + 4];
#pragma unroll
                for (int r = 0; r < 8; ++r) {
                    float xs = (i == 0) ? xv[r].x : (i == 1) ? xv[r].y
                             : (i == 2) ? xv[r].z : xv[r].w;
                    acc[r][0] = fmaf(xs, wa.x, acc[r][0]);
                    acc[r][1] = fmaf(xs, wa.y, acc[r][1]);
                    acc[r][2] = fmaf(xs, wa.z, acc[r][2]);
                    acc[r][3] = fmaf(xs, wa.w, acc[r][3]);
                    acc[r][4] = fmaf(xs, wb.x, acc[r][4]);
                    acc[r][5] = fmaf(xs, wb.y, acc[r][5]);
                    acc[r][6] = fmaf(xs, wb.z, acc[r][6]);
                    acc[r][7] = fmaf(xs, wb.w, acc[r][7]);
                }
            }
        }
        __syncthreads();
    }

    float4 b0 = *(const float4*)&bias[tj * 8];
    float4 b1 = *(const float4*)&bias[tj * 8 + 4];
#pragma unroll
    for (int r = 0; r < 8; ++r) {
        long row = r0 + tr * 8 + r;
        float4 o0, o1;
        o0.x = acc[r][0] + b0.x; o0.y = acc[r][1] + b0.y;
        o0.z = acc[r][2] + b0.z; o0.w = acc[r][3] + b0.w;
        o1.x = acc[r][4] + b1.x; o1.y = acc[r][5] + b1.y;
        o1.z = acc[r][6] + b1.z; o1.w = acc[r][7] + b1.w;
        *(float4*)&C[row * JD + tj * 8]     = o0;
        *(float4*)&C[row * JD + tj * 8 + 4] = o1;
    }
}

// ---------------------------------------------------------------------------
// GEMM2 via MFMA f16 (v6's verified fragment convention):
// out[r][j] = sum_k hidden[r][k] * W_fc[j][k] + b_fc[j].
// D = A(W_fc rows) x B(hidden cols). 2048 blocks x 256 thr (4 waves);
// wave = 16 r's x all 128 j (8 j-tiles); K = 8 steps of 32.
// Per kt: one B-frag (cvt fp32->f16 from 128B-coalesced hidden reads)
// feeds 8 MFMAs. A-frags stream from the 64KB L2-resident wfcp.
// Lane l: B-col/D-col = r0 + (l&15); D rows = (l>>4)*4 + reg.
// ---------------------------------------------------------------------------
__global__ __launch_bounds__(256, 4)
void gemm2_mfma(const float* __restrict__ hidden, const unsigned* __restrict__ wfcp,
                const float* __restrict__ b_fc, float* __restrict__ out) {
    const int tid = threadIdx.x;
    const int w   = tid >> 6;
    const int l   = tid & 63;
    const int krow = l >> 4;
    const long r  = (long)blockIdx.x * 64 + w * 16 + (l & 15);
    const float* __restrict__ hrow = hidden + r * HH;

    f32x4 acc[8];
#pragma unroll
    for (int jt = 0; jt < 8; ++jt) acc[jt] = (f32x4){0.f, 0.f, 0.f, 0.f};

#pragma unroll
    for (int kt = 0; kt < 8; ++kt) {
        float4 h0 = *(const float4*)&hrow[kt * 32 + krow * 8];
        float4 h1 = *(const float4*)&hrow[kt * 32 + krow * 8 + 4];
        half8 bf;
        bf[0] = (_Float16)h0.x; bf[1] = (_Float16)h0.y;
        bf[2] = (_Float16)h0.z; bf[3] = (_Float16)h0.w;
        bf[4] = (_Float16)h1.x; bf[5] = (_Float16)h1.y;
        bf[6] = (_Float16)h1.z; bf[7] = (_Float16)h1.w;
#pragma unroll
        for (int jt = 0; jt < 8; ++jt) {
            half8 af = *(const half8*)&wfcp[(size_t)((jt * 8 + kt) * 64 + l) * 4];
            acc[jt] = __builtin_amdgcn_mfma_f32_16x16x32_f16(af, bf, acc[jt], 0, 0, 0);
        }
    }

#pragma unroll
    for (int jt = 0; jt < 8; ++jt) {
        int j0 = jt * 16 + krow * 4;
        float4 bb = *(const float4*)&b_fc[j0];
        float4 o;
        o.x = acc[jt][0] + bb.x; o.y = acc[jt][1] + bb.y;
        o.z = acc[jt][2] + bb.z; o.w = acc[jt][3] + bb.w;
        *(float4*)&out[r * OO + j0] = o;
    }
}

// ---------------------------------------------------------------------------
// Sequential scan v9 (verbatim revert — best measured: 1256 us).
// 64 blocks x 512 threads, weights stream from L2 (swizzled, coalesced),
// double-buffered f16 h in LDS, butterfly shfl_xor(16,32) reduce,
// one barrier per step. MAC = builtin fdot2 (fastest measured: the
// v11-v13 instruction sweep showed dot2 930 < pk_fma 1116 < fma_mix 1479
// VALU-cyc/SIMD/step).
// ---------------------------------------------------------------------------
__global__ __attribute__((amdgpu_waves_per_eu(2, 2))) __launch_bounds__(512)
void rnn_scan(const unsigned* __restrict__ wsw, float* __restrict__ hid) {
    const int b   = blockIdx.x;
    const int tid = threadIdx.x;
    const int w   = tid >> 6;
    const int l   = tid & 63;
    const int sl  = l & 15;
    const int q   = l >> 4;

    const int j0 = w * 32 + sl * 2;      // two outputs j0, j0+1

    __shared__ __align__(16) unsigned h16[2][4 * 36];

    // per-thread weight stream base: lane-consecutive 16B chunks
    const uint4* __restrict__ wp = (const uint4*)wsw + ((size_t)w << 10) + l;

    for (int i = tid; i < 2 * 4 * 36; i += 512) ((unsigned*)h16)[i] = 0u;

    float* __restrict__ base = hid + (size_t)b * SS * HH;
    float2 xp0 = *(const float2*)&base[j0];
    float2 xp1 = *(const float2*)&base[HH + j0];
    __syncthreads();

#pragma unroll 1
    for (int t = 0; t < SS; ++t) {
        // weight stream for this step (L2-resident, coalesced)
        uint4 wA[8], wB[8];
#pragma unroll
        for (int i = 0; i < 8; ++i) {
            wA[i] = wp[i * 64];
            wB[i] = wp[(8 + i) * 64];
        }

        // prefetch xproj for t+2 (read precedes the overwrite at t)
        float2 xp2 = make_float2(0.f, 0.f);
        if (t + 2 < SS) xp2 = *(const float2*)&base[(size_t)(t + 2) * HH + j0];

        const uint4* hb = (const uint4*)&h16[t & 1][q * 36];
        float aA0 = 0.f, aA1 = 0.f, aB0 = 0.f, aB1 = 0.f;
#pragma unroll
        for (int i = 0; i < 8; ++i) {
            uint4 hv = hb[i];
            aA0 = fdot2(hv.x, wA[i].x, aA0);
            aA1 = fdot2(hv.y, wA[i].y, aA1);
            aA0 = fdot2(hv.z, wA[i].z, aA0);
            aA1 = fdot2(hv.w, wA[i].w, aA1);
            aB0 = fdot2(hv.x, wB[i].x, aB0);
            aB1 = fdot2(hv.y, wB[i].y, aB1);
            aB0 = fdot2(hv.z, wB[i].z, aB0);
            aB1 = fdot2(hv.w, wB[i].w, aB1);
        }
        float sA = aA0 + aA1;
        float sB = aB0 + aB1;
        // butterfly over the 4 k-quarters (lanes sl, sl+16, sl+32, sl+48)
        sA += __shfl_xor(sA, 16, 64);
        sA += __shfl_xor(sA, 32, 64);
        sB += __shfl_xor(sB, 16, 64);
        sB += __shfl_xor(sB, 32, 64);

        float s0 = xp0.x + sA;
        float s1 = xp0.y + sB;
        // tanh(s) = 1 - 2/(e^{2s}+1); overflow-safe without clamps
        float e0  = __expf(2.0f * s0);
        float e1  = __expf(2.0f * s1);
        float hn0 = 1.0f - __fdividef(2.0f, e0 + 1.0f);
        float hn1 = 1.0f - __fdividef(2.0f, e1 + 1.0f);

        if (q == 0) {
            union { h2_t h; unsigned u; } pk;
            pk.h.x = (_Float16)hn0;
            pk.h.y = (_Float16)hn1;
            const int W = j0 >> 1;
            h16[(t & 1) ^ 1][(W >> 5) * 36 + (W & 31)] = pk.u;
            *(float2*)&base[(size_t)t * HH + j0] = make_float2(hn0, hn1);
        }
        __syncthreads();
        xp0 = xp1;
        xp1 = xp2;
    }
}

// ---------------------------------------------------------------------------
extern "C" void kernel_launch(void* const* d_in, const int* in_sizes, int n_in,
                              void* d_out, int out_size, void* d_ws, size_t ws_size,
                              hipStream_t stream) {
    const float* x    = (const float*)d_in[0];
    const float* W_ih = (const float*)d_in[1];
    const float* W_hh = (const float*)d_in[2];
    const float* b_ih = (const float*)d_in[3];
    const float* b_hh = (const float*)d_in[4];
    const float* W_fc = (const float*)d_in[5];
    const float* b_fc = (const float*)d_in[6];

    float* out_fc  = (float*)d_out;                          // [B][S][O]
    float* hidden  = (float*)d_out + (size_t)BB * SS * OO;   // [B][S][H]

    float*    wihT  = (float*)d_ws;                   // [I][H]   32768 f
    float*    biasc = wihT + II * HH;                 // [H]        256 f
    unsigned* wsw   = (unsigned*)(biasc + HH);        // scan wts 32768 u32
    unsigned* wfcp  = wsw + HH * (HH / 2);            // W_fc frags 16384 u32

    const long NR = (long)BB * SS;                    // 131072 rows

    prep_kernel<<<128, 256, 0, stream>>>(W_ih, b_ih, b_hh, W_fc,
                                         wihT, biasc, wsw, wfcp, W_hh);
    gemm_rk<II, HH, 64><<<NR / 64, 256, 0, stream>>>(x, wihT, biasc, hidden);
    rnn_scan<<<BB, 512, 0, stream>>>(wsw, hidden);
    gemm2_mfma<<<NR / 64, 256, 0, stream>>>(hidden, wfcp, b_fc, out_fc);
}

// Round 22
// 1353.406 us; speedup vs baseline: 1.6329x; 1.0325x over previous
//
#include <hip/hip_runtime.h>

#define BB 64
#define SS 2048
#define II 128
#define HH 256
#define OO 128

typedef _Float16 h2_t  __attribute__((ext_vector_type(2)));
typedef _Float16 half8 __attribute__((ext_vector_type(8)));
typedef float    f32x4 __attribute__((ext_vector_type(4)));

__device__ __forceinline__ h2_t u2h(unsigned u) {
    union { unsigned u; h2_t h; } c; c.u = u; return c.h;
}

#if __has_builtin(__builtin_amdgcn_fdot2)
__device__ __forceinline__ float fdot2(unsigned h, unsigned w, float acc) {
    return __builtin_amdgcn_fdot2(u2h(h), u2h(w), acc, false);
}
#else
__device__ __forceinline__ float fdot2(unsigned h, unsigned w, float acc) {
    h2_t hh = u2h(h), ww = u2h(w);
    acc = fmaf((float)hh.x, (float)hh.x * 0.f + (float)ww.x, acc); // unreachable on gfx950
    acc = fmaf((float)hh.y, (float)ww.y, acc);
    return acc;
}
#endif

// ---------------------------------------------------------------------------
// Prep: combine biases, write swizzled scan weights wsw (v9 layout),
// pack W_fc into MFMA A-fragment order wfcp (gemm2), and pack W_ih into
// MFMA A-fragment order wihp (gemm1):
//   wihp uint4 slot s = (jt*4 + kt)*64 + l holds A[row = jt*16 + (l&15)]
//   [k = kt*32 + (l>>4)*8 .. +7] as 8 f16. (jt: 16 tiles over H=256,
//   kt: 4 steps over I=128.)
// ---------------------------------------------------------------------------
__global__ void prep_kernel(const float* __restrict__ W_ih, const float* __restrict__ b_ih,
                            const float* __restrict__ b_hh, const float* __restrict__ W_fc,
                            float* __restrict__ biasc, unsigned* __restrict__ wsw,
                            unsigned* __restrict__ wfcp, unsigned* __restrict__ wihp,
                            const float* __restrict__ W_hh) {
    int idx = blockIdx.x * 256 + threadIdx.x;      // grid 128*256 = 32768
    if (idx < HH * (HH / 2)) {      // swizzled scan weights (32768 dwords)
        int d   = idx & 3;
        int s   = idx >> 2;
        int l   = s & 63;
        int rem = s >> 6;
        int i    = rem & 7;
        int pair = (rem >> 3) & 1;
        int w    = rem >> 4;
        int j    = w * 32 + (l & 15) * 2 + pair;
        int word = (l >> 4) * 32 + i * 4 + d;      // dword index within row j
        union { h2_t h; unsigned u; } pk;
        pk.h.x = (_Float16)W_hh[j * HH + 2 * word];
        pk.h.y = (_Float16)W_hh[j * HH + 2 * word + 1];
        wsw[idx] = pk.u;
    }
    if (idx < 8 * 8 * 64 * 4) {     // wfcp: W_fc MFMA fragments (16384 dwords)
        int d    = idx & 3;
        int slot = idx >> 2;
        int l    = slot & 63;
        int kt   = (slot >> 6) & 7;
        int jt   = slot >> 9;
        int j    = jt * 16 + (l & 15);
        int k0   = kt * 32 + (l >> 4) * 8 + d * 2;
        union { h2_t h; unsigned u; } pk;
        pk.h.x = (_Float16)W_fc[j * HH + k0];
        pk.h.y = (_Float16)W_fc[j * HH + k0 + 1];
        wfcp[idx] = pk.u;
    }
    if (idx < 16 * 4 * 64 * 4) {    // wihp: W_ih MFMA fragments (16384 dwords)
        int d    = idx & 3;
        int slot = idx >> 2;
        int l    = slot & 63;
        int kt   = (slot >> 6) & 3;
        int jt   = slot >> 8;
        int j    = jt * 16 + (l & 15);
        int k0   = kt * 32 + (l >> 4) * 8 + d * 2;
        union { h2_t h; unsigned u; } pk;
        pk.h.x = (_Float16)W_ih[j * II + k0];
        pk.h.y = (_Float16)W_ih[j * II + k0 + 1];
        wihp[idx] = pk.u;
    }
    if (idx < HH) biasc[idx] = b_ih[idx] + b_hh[idx];
}

// ---------------------------------------------------------------------------
// GEMM1 via MFMA f16 (clone of the HW-verified gemm2 convention):
// xproj[r][j] = sum_k x[r][k] * W_ih[j][k] + biasc[j].  M=131072, N=256,
// K=128. 2048 blocks x 256 thr (4 waves); wave = 16 r's x all 256 j
// (16 j-tiles); K = 4 steps of 32. Per kt: one B-frag (cvt fp32->f16 from
// x) feeds 16 MFMAs; A-frags stream from the 64KB L2-resident wihp.
// ---------------------------------------------------------------------------
__global__ __launch_bounds__(256, 4)
void gemm1_mfma(const float* __restrict__ x, const unsigned* __restrict__ wihp,
                const float* __restrict__ biasc, float* __restrict__ xproj) {
    const int tid = threadIdx.x;
    const int w   = tid >> 6;
    const int l   = tid & 63;
    const int krow = l >> 4;
    const long r  = (long)blockIdx.x * 64 + w * 16 + (l & 15);
    const float* __restrict__ xrow = x + r * II;

    f32x4 acc[16];
#pragma unroll
    for (int jt = 0; jt < 16; ++jt) acc[jt] = (f32x4){0.f, 0.f, 0.f, 0.f};

#pragma unroll
    for (int kt = 0; kt < 4; ++kt) {
        float4 h0 = *(const float4*)&xrow[kt * 32 + krow * 8];
        float4 h1 = *(const float4*)&xrow[kt * 32 + krow * 8 + 4];
        half8 bf;
        bf[0] = (_Float16)h0.x; bf[1] = (_Float16)h0.y;
        bf[2] = (_Float16)h0.z; bf[3] = (_Float16)h0.w;
        bf[4] = (_Float16)h1.x; bf[5] = (_Float16)h1.y;
        bf[6] = (_Float16)h1.z; bf[7] = (_Float16)h1.w;
#pragma unroll
        for (int jt = 0; jt < 16; ++jt) {
            half8 af = *(const half8*)&wihp[(size_t)((jt * 4 + kt) * 64 + l) * 4];
            acc[jt] = __builtin_amdgcn_mfma_f32_16x16x32_f16(af, bf, acc[jt], 0, 0, 0);
        }
    }

#pragma unroll
    for (int jt = 0; jt < 16; ++jt) {
        int j0 = jt * 16 + krow * 4;
        float4 bb = *(const float4*)&biasc[j0];
        float4 o;
        o.x = acc[jt][0] + bb.x; o.y = acc[jt][1] + bb.y;
        o.z = acc[jt][2] + bb.z; o.w = acc[jt][3] + bb.w;
        *(float4*)&xproj[r * HH + j0] = o;
    }
}

// ---------------------------------------------------------------------------
// GEMM2 via MFMA f16 (HW-verified in v14): out[r][j] = sum_k hidden[r][k]
// * W_fc[j][k] + b_fc[j]. 2048 blocks x 256 thr; wave = 16 r's x 128 j.
// ---------------------------------------------------------------------------
__global__ __launch_bounds__(256, 4)
void gemm2_mfma(const float* __restrict__ hidden, const unsigned* __restrict__ wfcp,
                const float* __restrict__ b_fc, float* __restrict__ out) {
    const int tid = threadIdx.x;
    const int w   = tid >> 6;
    const int l   = tid & 63;
    const int krow = l >> 4;
    const long r  = (long)blockIdx.x * 64 + w * 16 + (l & 15);
    const float* __restrict__ hrow = hidden + r * HH;

    f32x4 acc[8];
#pragma unroll
    for (int jt = 0; jt < 8; ++jt) acc[jt] = (f32x4){0.f, 0.f, 0.f, 0.f};

#pragma unroll
    for (int kt = 0; kt < 8; ++kt) {
        float4 h0 = *(const float4*)&hrow[kt * 32 + krow * 8];
        float4 h1 = *(const float4*)&hrow[kt * 32 + krow * 8 + 4];
        half8 bf;
        bf[0] = (_Float16)h0.x; bf[1] = (_Float16)h0.y;
        bf[2] = (_Float16)h0.z; bf[3] = (_Float16)h0.w;
        bf[4] = (_Float16)h1.x; bf[5] = (_Float16)h1.y;
        bf[6] = (_Float16)h1.z; bf[7] = (_Float16)h1.w;
#pragma unroll
        for (int jt = 0; jt < 8; ++jt) {
            half8 af = *(const half8*)&wfcp[(size_t)((jt * 8 + kt) * 64 + l) * 4];
            acc[jt] = __builtin_amdgcn_mfma_f32_16x16x32_f16(af, bf, acc[jt], 0, 0, 0);
        }
    }

#pragma unroll
    for (int jt = 0; jt < 8; ++jt) {
        int j0 = jt * 16 + krow * 4;
        float4 bb = *(const float4*)&b_fc[j0];
        float4 o;
        o.x = acc[jt][0] + bb.x; o.y = acc[jt][1] + bb.y;
        o.z = acc[jt][2] + bb.z; o.w = acc[jt][3] + bb.w;
        *(float4*)&out[r * OO + j0] = o;
    }
}

// ---------------------------------------------------------------------------
// Sequential scan v9 (unchanged — best measured: 1252 us; the v11-v13
// instruction sweep confirmed builtin-dot2 is the fastest MAC config).
// 64 blocks x 512 threads, weights stream from L2 (swizzled, coalesced),
// double-buffered f16 h in LDS, butterfly shfl_xor(16,32) reduce,
// one barrier per step.
// ---------------------------------------------------------------------------
__global__ __attribute__((amdgpu_waves_per_eu(2, 2))) __launch_bounds__(512)
void rnn_scan(const unsigned* __restrict__ wsw, float* __restrict__ hid) {
    const int b   = blockIdx.x;
    const int tid = threadIdx.x;
    const int w   = tid >> 6;
    const int l   = tid & 63;
    const int sl  = l & 15;
    const int q   = l >> 4;

    const int j0 = w * 32 + sl * 2;      // two outputs j0, j0+1

    __shared__ __align__(16) unsigned h16[2][4 * 36];

    // per-thread weight stream base: lane-consecutive 16B chunks
    const uint4* __restrict__ wp = (const uint4*)wsw + ((size_t)w << 10) + l;

    for (int i = tid; i < 2 * 4 * 36; i += 512) ((unsigned*)h16)[i] = 0u;

    float* __restrict__ base = hid + (size_t)b * SS * HH;
    float2 xp0 = *(const float2*)&base[j0];
    float2 xp1 = *(const float2*)&base[HH + j0];
    __syncthreads();

#pragma unroll 1
    for (int t = 0; t < SS; ++t) {
        // weight stream for this step (L2-resident, coalesced)
        uint4 wA[8], wB[8];
#pragma unroll
        for (int i = 0; i < 8; ++i) {
            wA[i] = wp[i * 64];
            wB[i] = wp[(8 + i) * 64];
        }

        // prefetch xproj for t+2 (read precedes the overwrite at t)
        float2 xp2 = make_float2(0.f, 0.f);
        if (t + 2 < SS) xp2 = *(const float2*)&base[(size_t)(t + 2) * HH + j0];

        const uint4* hb = (const uint4*)&h16[t & 1][q * 36];
        float aA0 = 0.f, aA1 = 0.f, aB0 = 0.f, aB1 = 0.f;
#pragma unroll
        for (int i = 0; i < 8; ++i) {
            uint4 hv = hb[i];
            aA0 = fdot2(hv.x, wA[i].x, aA0);
            aA1 = fdot2(hv.y, wA[i].y, aA1);
            aA0 = fdot2(hv.z, wA[i].z, aA0);
            aA1 = fdot2(hv.w, wA[i].w, aA1);
            aB0 = fdot2(hv.x, wB[i].x, aB0);
            aB1 = fdot2(hv.y, wB[i].y, aB1);
            aB0 = fdot2(hv.z, wB[i].z, aB0);
            aB1 = fdot2(hv.w, wB[i].w, aB1);
        }
        float sA = aA0 + aA1;
        float sB = aB0 + aB1;
        // butterfly over the 4 k-quarters (lanes sl, sl+16, sl+32, sl+48)
        sA += __shfl_xor(sA, 16, 64);
        sA += __shfl_xor(sA, 32, 64);
        sB += __shfl_xor(sB, 16, 64);
        sB += __shfl_xor(sB, 32, 64);

        float s0 = xp0.x + sA;
        float s1 = xp0.y + sB;
        // tanh(s) = 1 - 2/(e^{2s}+1); overflow-safe without clamps
        float e0  = __expf(2.0f * s0);
        float e1  = __expf(2.0f * s1);
        float hn0 = 1.0f - __fdividef(2.0f, e0 + 1.0f);
        float hn1 = 1.0f - __fdividef(2.0f, e1 + 1.0f);

        if (q == 0) {
            union { h2_t h; unsigned u; } pk;
            pk.h.x = (_Float16)hn0;
            pk.h.y = (_Float16)hn1;
            const int W = j0 >> 1;
            h16[(t & 1) ^ 1][(W >> 5) * 36 + (W & 31)] = pk.u;
            *(float2*)&base[(size_t)t * HH + j0] = make_float2(hn0, hn1);
        }
        __syncthreads();
        xp0 = xp1;
        xp1 = xp2;
    }
}

// ---------------------------------------------------------------------------
extern "C" void kernel_launch(void* const* d_in, const int* in_sizes, int n_in,
                              void* d_out, int out_size, void* d_ws, size_t ws_size,
                              hipStream_t stream) {
    const float* x    = (const float*)d_in[0];
    const float* W_ih = (const float*)d_in[1];
    const float* W_hh = (const float*)d_in[2];
    const float* b_ih = (const float*)d_in[3];
    const float* b_hh = (const float*)d_in[4];
    const float* W_fc = (const float*)d_in[5];
    const float* b_fc = (const float*)d_in[6];

    float* out_fc  = (float*)d_out;                          // [B][S][O]
    float* hidden  = (float*)d_out + (size_t)BB * SS * OO;   // [B][S][H]

    float*    biasc = (float*)d_ws;                   // [H]        256 f
    unsigned* wsw   = (unsigned*)(biasc + HH);        // scan wts 32768 u32
    unsigned* wfcp  = wsw + HH * (HH / 2);            // W_fc frags 16384 u32
    unsigned* wihp  = wfcp + 8 * 8 * 64 * 4;          // W_ih frags 16384 u32

    const long NR = (long)BB * SS;                    // 131072 rows

    prep_kernel<<<128, 256, 0, stream>>>(W_ih, b_ih, b_hh, W_fc,
                                         biasc, wsw, wfcp, wihp, W_hh);
    gemm1_mfma<<<NR / 64, 256, 0, stream>>>(x, wihp, biasc, hidden);
    rnn_scan<<<BB, 512, 0, stream>>>(wsw, hidden);
    gemm2_mfma<<<NR / 64, 256, 0, stream>>>(hidden, wfcp, b_fc, out_fc);
}